// Round 4
// baseline (450.032 us; speedup 1.0000x reference)
//
#include <hip/hip_runtime.h>
#include <math.h>

#define D_DIM 256
#define H_DIM 128
#define TILE  32
#define HPAD  264   // shorts per LDS row: stride 528 B -> minimal b128 aliasing

typedef __attribute__((ext_vector_type(8))) short bf16x8;
typedef __attribute__((ext_vector_type(4))) float f32x4;

__device__ __forceinline__ unsigned short f32_to_bf16(float f) {
  unsigned int u = __float_as_uint(f);
  u += 0x7FFFu + ((u >> 16) & 1u);          // RTNE (setup kernel only)
  return (unsigned short)(u >> 16);
}

// hi = truncate-to-bf16 (AND); residual r for the lo term. x ~= hi+lo to 2^-14.
__device__ __forceinline__ unsigned int pack_hi2(float f0, float f1, float& r0, float& r1) {
  unsigned int u0 = __float_as_uint(f0) & 0xFFFF0000u;
  unsigned int u1 = __float_as_uint(f1) & 0xFFFF0000u;
  r0 = f0 - __uint_as_float(u0);
  r1 = f1 - __uint_as_float(u1);
  return (u0 >> 16) | u1;
}
__device__ __forceinline__ unsigned int pack_lo2(float r0, float r1) {
  return (__float_as_uint(r0) >> 16) | (__float_as_uint(r1) & 0xFFFF0000u);
}

__device__ __forceinline__ float tanh_fast(float x) {
  float e = __expf(2.0f * x);
  return 1.0f - 2.0f / (e + 1.0f);
}

// ---------------------------------------------------------------------------
// Setup: pre-swizzle W1 into per-lane bf16 B-fragments (see R2 comment).
// ---------------------------------------------------------------------------
__global__ void setup_w1_kernel(const float* __restrict__ W1,
                                unsigned short* __restrict__ wfrag)
{
  const int t = threadIdx.x;
  const int l = t & 63, w = t >> 6;
  const int q = l >> 4, c = l & 15;
#pragma unroll
  for (int kt = 0; kt < 8; ++kt)
#pragma unroll
    for (int nt = 0; nt < 2; ++nt) {
      int f = kt * 2 + nt;
      int col = w * 32 + nt * 16 + c;
#pragma unroll
      for (int j = 0; j < 8; ++j) {
        int k = kt * 32 + q * 8 + j;
        wfrag[((size_t)f * 256 + t) * 8 + j] = f32_to_bf16(W1[k * H_DIM + col]);
      }
    }
}

// ---------------------------------------------------------------------------
// Segment start offsets (batch sorted; int32/int64 runtime detect).
// ---------------------------------------------------------------------------
__global__ void offsets_kernel(const void* __restrict__ batch, int* __restrict__ start,
                               int N, int G)
{
  int g = blockIdx.x * blockDim.x + threadIdx.x;
  if (g > G) return;
  const int* b32 = (const int*)batch;
  bool is64 = (b32[N - 1] != G - 1);
  int lo = 0, hi = N;
  while (lo < hi) {
    int mid = (lo + hi) >> 1;
    long long v = is64 ? ((const long long*)batch)[mid] : (long long)b32[mid];
    if (v < (long long)g) lo = mid + 1; else hi = mid;
  }
  start[g] = lo;
}

// ---------------------------------------------------------------------------
// Fused single-pass, block per graph, 32-node tiles.
//  - x -> LDS bf16 hi/lo (converted once per element)
//  - MFMA logits (W1 frags in 64 VGPR), tanh+W2 reduce -> part[]
//  - online softmax + pool, FULLY UNROLLED (pads contribute exact zeros)
//  - T14: next tile's global loads issued before MFMA, LDS-written after pool
// ---------------------------------------------------------------------------
__global__ __launch_bounds__(256, 3)
void fused_kernel(const float* __restrict__ x, const unsigned short* __restrict__ wfrag,
                  const float* __restrict__ b1, const float* __restrict__ W2,
                  const int* __restrict__ start, float* __restrict__ out, int N)
{
  __shared__ unsigned short xhi[TILE][HPAD];  // 16.9 KB
  __shared__ unsigned short xlo[TILE][HPAD];  // 16.9 KB
  __shared__ float part[4][TILE];

  const int g = blockIdx.x;
  const int tid = threadIdx.x;
  const int s = start[g], e = start[g + 1];
  if (s >= e) { out[(size_t)g * D_DIM + tid] = 0.0f; return; }
  const int len = e - s;

  const int lane = tid & 63, w = tid >> 6;
  const int q = lane >> 4, c = lane & 15;
  const int srow = tid >> 5, scol8 = (tid & 31) * 8;   // staging coords (row += 8/iter)

  // W1 B-fragments: 16 x bf16x8 = 64 VGPR (coalesced, L2-resident)
  bf16x8 wf[8][2];
#pragma unroll
  for (int kt = 0; kt < 8; ++kt)
#pragma unroll
    for (int nt = 0; nt < 2; ++nt)
      wf[kt][nt] = ((const bf16x8*)wfrag)[(kt * 2 + nt) * 256 + tid];

  float b1c[2], w2c[2];
#pragma unroll
  for (int nt = 0; nt < 2; ++nt) {
    int col = w * 32 + nt * 16 + c;
    b1c[nt] = b1[col];
    w2c[nt] = W2[col];
  }

  float m_run = -INFINITY, Z = 0.0f, accd = 0.0f;
  const int nT = (len + TILE - 1) / TILE;

  // ---- prologue: stage tile 0 ----
#pragma unroll
  for (int it = 0; it < 4; ++it) {
    int row = srow + it * 8;
    int gr = min(s + row, N - 1);
    const float4* gp = reinterpret_cast<const float4*>(x + (size_t)gr * D_DIM + scol8);
    float4 A = gp[0], B = gp[1];
    float r0, r1, r2, r3, r4, r5, r6, r7;
    uint4 H, L;
    H.x = pack_hi2(A.x, A.y, r0, r1);  H.y = pack_hi2(A.z, A.w, r2, r3);
    H.z = pack_hi2(B.x, B.y, r4, r5);  H.w = pack_hi2(B.z, B.w, r6, r7);
    L.x = pack_lo2(r0, r1);  L.y = pack_lo2(r2, r3);
    L.z = pack_lo2(r4, r5);  L.w = pack_lo2(r6, r7);
    *reinterpret_cast<uint4*>(&xhi[row][scol8]) = H;
    *reinterpret_cast<uint4*>(&xlo[row][scol8]) = L;
  }

  for (int ti = 0; ti < nT; ++ti) {
    const int t0 = ti * TILE;
    const int iend = min(TILE, len - t0);
    const bool haveNext = (ti + 1 < nT);

    __syncthreads();   // LDS tile ti ready

    // ---- T14: issue next tile's global loads early (regs) ----
    float4 pf[4][2];
    if (haveNext) {
#pragma unroll
      for (int it = 0; it < 4; ++it) {
        int row = srow + it * 8;
        int gr = min(s + t0 + TILE + row, N - 1);
        const float4* gp = reinterpret_cast<const float4*>(x + (size_t)gr * D_DIM + scol8);
        pf[it][0] = gp[0];
        pf[it][1] = gp[1];
      }
    }

    // ---- MFMA: h-tile = x_tile @ W1[:, wave's 32 cols] (hi + lo terms) ----
    f32x4 acc[2][2];
#pragma unroll
    for (int m = 0; m < 2; ++m)
#pragma unroll
      for (int nt = 0; nt < 2; ++nt) acc[m][nt] = (f32x4){0.f, 0.f, 0.f, 0.f};

#pragma unroll
    for (int kt = 0; kt < 8; ++kt) {
      const int koff = kt * 32 + q * 8;
      bf16x8 ah0 = *reinterpret_cast<const bf16x8*>(&xhi[c][koff]);
      bf16x8 al0 = *reinterpret_cast<const bf16x8*>(&xlo[c][koff]);
      bf16x8 ah1 = *reinterpret_cast<const bf16x8*>(&xhi[16 + c][koff]);
      bf16x8 al1 = *reinterpret_cast<const bf16x8*>(&xlo[16 + c][koff]);
#pragma unroll
      for (int nt = 0; nt < 2; ++nt) {
        acc[0][nt] = __builtin_amdgcn_mfma_f32_16x16x32_bf16(ah0, wf[kt][nt], acc[0][nt], 0, 0, 0);
        acc[0][nt] = __builtin_amdgcn_mfma_f32_16x16x32_bf16(al0, wf[kt][nt], acc[0][nt], 0, 0, 0);
        acc[1][nt] = __builtin_amdgcn_mfma_f32_16x16x32_bf16(ah1, wf[kt][nt], acc[1][nt], 0, 0, 0);
        acc[1][nt] = __builtin_amdgcn_mfma_f32_16x16x32_bf16(al1, wf[kt][nt], acc[1][nt], 0, 0, 0);
      }
    }

    // ---- tanh + W2 dot; reduce across the 16 col-lanes -> part[w][i] ----
#pragma unroll
    for (int m = 0; m < 2; ++m)
#pragma unroll
      for (int r = 0; r < 4; ++r) {
        float v = tanh_fast(acc[m][0][r] + b1c[0]) * w2c[0]
                + tanh_fast(acc[m][1][r] + b1c[1]) * w2c[1];
#pragma unroll
        for (int o = 1; o < 16; o <<= 1) v += __shfl_xor(v, o, 64);
        if (c == 0) part[w][m * 16 + q * 4 + r] = v;
      }
    __syncthreads();   // part ready

    // ---- online softmax + pool: FIXED 32 iterations (pads are exact +0) ----
    {
      const int i = lane & 31;
      float li = (i < iend) ? (part[0][i] + part[1][i] + part[2][i] + part[3][i])
                            : -INFINITY;
      float tmax = li;
#pragma unroll
      for (int o = 1; o < 32; o <<= 1) tmax = fmaxf(tmax, __shfl_xor(tmax, o, 64));
      float m_new = fmaxf(m_run, tmax);
      float ei = __expf(li - m_new);              // 0 for pad lanes
      float esum = ei;
#pragma unroll
      for (int o = 1; o < 32; o <<= 1) esum += __shfl_xor(esum, o, 64);
      float scale = __expf(m_run - m_new);        // first tile: exp(-inf)=0
      Z = Z * scale + esum;

      float ac0 = 0.f, ac1 = 0.f, ac2 = 0.f, ac3 = 0.f;
#pragma unroll
      for (int ii = 0; ii < TILE; ii += 4) {
        float e0 = __shfl(ei, ii + 0, 64);
        float e1 = __shfl(ei, ii + 1, 64);
        float e2 = __shfl(ei, ii + 2, 64);
        float e3 = __shfl(ei, ii + 3, 64);
        float x0 = __uint_as_float((unsigned int)xhi[ii + 0][tid] << 16)
                 + __uint_as_float((unsigned int)xlo[ii + 0][tid] << 16);
        float x1 = __uint_as_float((unsigned int)xhi[ii + 1][tid] << 16)
                 + __uint_as_float((unsigned int)xlo[ii + 1][tid] << 16);
        float x2 = __uint_as_float((unsigned int)xhi[ii + 2][tid] << 16)
                 + __uint_as_float((unsigned int)xlo[ii + 2][tid] << 16);
        float x3 = __uint_as_float((unsigned int)xhi[ii + 3][tid] << 16)
                 + __uint_as_float((unsigned int)xlo[ii + 3][tid] << 16);
        ac0 = fmaf(e0, x0, ac0);
        ac1 = fmaf(e1, x1, ac1);
        ac2 = fmaf(e2, x2, ac2);
        ac3 = fmaf(e3, x3, ac3);
      }
      accd = fmaf(accd, scale, (ac0 + ac1) + (ac2 + ac3));
      m_run = m_new;
    }
    __syncthreads();   // pool done; LDS free to overwrite

    // ---- write prefetched tile ti+1 ----
    if (haveNext) {
#pragma unroll
      for (int it = 0; it < 4; ++it) {
        int row = srow + it * 8;
        float4 A = pf[it][0], B = pf[it][1];
        float r0, r1, r2, r3, r4, r5, r6, r7;
        uint4 H, L;
        H.x = pack_hi2(A.x, A.y, r0, r1);  H.y = pack_hi2(A.z, A.w, r2, r3);
        H.z = pack_hi2(B.x, B.y, r4, r5);  H.w = pack_hi2(B.z, B.w, r6, r7);
        L.x = pack_lo2(r0, r1);  L.y = pack_lo2(r2, r3);
        L.z = pack_lo2(r4, r5);  L.w = pack_lo2(r6, r7);
        *reinterpret_cast<uint4*>(&xhi[row][scol8]) = H;
        *reinterpret_cast<uint4*>(&xlo[row][scol8]) = L;
      }
    }
  }

  out[(size_t)g * D_DIM + tid] = accd / Z;
}

// ---------------------------------------------------------------------------
extern "C" void kernel_launch(void* const* d_in, const int* in_sizes, int n_in,
                              void* d_out, int out_size, void* d_ws, size_t ws_size,
                              hipStream_t stream)
{
  const float* x     = (const float*)d_in[0];
  const void*  batch = d_in[1];
  const float* W1    = (const float*)d_in[2];
  const float* b1    = (const float*)d_in[3];
  const float* W2    = (const float*)d_in[4];
  // d_in[5] = b2: cancels exactly in the segment softmax -> unused.

  const int N = in_sizes[0] / D_DIM;     // 500000
  const int G = out_size / D_DIM;        // 4096

  unsigned short* wfrag = (unsigned short*)d_ws;              // 64 KB
  int* startA = (int*)((char*)d_ws + 16 * 256 * 8 * sizeof(unsigned short));
  float* out = (float*)d_out;

  setup_w1_kernel<<<1, 256, 0, stream>>>(W1, wfrag);
  offsets_kernel<<<(G + 1 + 255) / 256, 256, 0, stream>>>(batch, startA, N, G);
  fused_kernel<<<G, 256, 0, stream>>>(x, wfrag, b1, W2, startA, out, N);
}

// Round 5
// 195.620 us; speedup vs baseline: 2.3005x; 2.3005x over previous
//
#include <hip/hip_runtime.h>
#include <math.h>

#define D_DIM 256
#define H_DIM 128
#define TILE  32
#define HPAD  264   // shorts per LDS row: stride 528 B -> 2-way max aliasing (free)

typedef __attribute__((ext_vector_type(8))) short bf16x8;
typedef __attribute__((ext_vector_type(4))) float f32x4;

__device__ __forceinline__ unsigned short f32_to_bf16(float f) {
  unsigned int u = __float_as_uint(f);
  u += 0x7FFFu + ((u >> 16) & 1u);          // RTNE (setup kernel only)
  return (unsigned short)(u >> 16);
}

// hi = truncate-to-bf16 (AND); residual r for the lo term. x ~= hi+lo to 2^-14.
__device__ __forceinline__ unsigned int pack_hi2(float f0, float f1, float& r0, float& r1) {
  unsigned int u0 = __float_as_uint(f0) & 0xFFFF0000u;
  unsigned int u1 = __float_as_uint(f1) & 0xFFFF0000u;
  r0 = f0 - __uint_as_float(u0);
  r1 = f1 - __uint_as_float(u1);
  return (u0 >> 16) | u1;
}
__device__ __forceinline__ unsigned int pack_lo2(float r0, float r1) {
  return (__float_as_uint(r0) >> 16) | (__float_as_uint(r1) & 0xFFFF0000u);
}

__device__ __forceinline__ float tanh_fast(float x) {
  float e = __expf(2.0f * x);
  return 1.0f - 2.0f / (e + 1.0f);
}

// ---------------------------------------------------------------------------
// Setup: pre-swizzle W1 into per-lane bf16 B-fragments (see R2 comment).
// ---------------------------------------------------------------------------
__global__ void setup_w1_kernel(const float* __restrict__ W1,
                                unsigned short* __restrict__ wfrag)
{
  const int t = threadIdx.x;
  const int l = t & 63, w = t >> 6;
  const int q = l >> 4, c = l & 15;
#pragma unroll
  for (int kt = 0; kt < 8; ++kt)
#pragma unroll
    for (int nt = 0; nt < 2; ++nt) {
      int f = kt * 2 + nt;
      int col = w * 32 + nt * 16 + c;
#pragma unroll
      for (int j = 0; j < 8; ++j) {
        int k = kt * 32 + q * 8 + j;
        wfrag[((size_t)f * 256 + t) * 8 + j] = f32_to_bf16(W1[k * H_DIM + col]);
      }
    }
}

// ---------------------------------------------------------------------------
// Segment start offsets (batch sorted; int32/int64 runtime detect).
// ---------------------------------------------------------------------------
__global__ void offsets_kernel(const void* __restrict__ batch, int* __restrict__ start,
                               int N, int G)
{
  int g = blockIdx.x * blockDim.x + threadIdx.x;
  if (g > G) return;
  const int* b32 = (const int*)batch;
  bool is64 = (b32[N - 1] != G - 1);
  int lo = 0, hi = N;
  while (lo < hi) {
    int mid = (lo + hi) >> 1;
    long long v = is64 ? ((const long long*)batch)[mid] : (long long)b32[mid];
    if (v < (long long)g) lo = mid + 1; else hi = mid;
  }
  start[g] = lo;
}

// convert one 8-f32 chunk to bf16 hi/lo and store to the LDS tile
__device__ __forceinline__ void convert_store(unsigned short (*xh)[HPAD],
                                              unsigned short (*xl)[HPAD],
                                              int row, int col8, float4 A, float4 B)
{
  float r0, r1, r2, r3, r4, r5, r6, r7;
  uint4 H, L;
  H.x = pack_hi2(A.x, A.y, r0, r1);  H.y = pack_hi2(A.z, A.w, r2, r3);
  H.z = pack_hi2(B.x, B.y, r4, r5);  H.w = pack_hi2(B.z, B.w, r6, r7);
  L.x = pack_lo2(r0, r1);  L.y = pack_lo2(r2, r3);
  L.z = pack_lo2(r4, r5);  L.w = pack_lo2(r6, r7);
  *reinterpret_cast<uint4*>(&xh[row][col8]) = H;
  *reinterpret_cast<uint4*>(&xl[row][col8]) = L;
}

// ---------------------------------------------------------------------------
// Fused single-pass, block per graph, 32-node tiles.
//  - x -> LDS bf16 hi/lo (converted once per element)
//  - MFMA logits (W1 frags in 64 VGPR), tanh+W2 reduce -> part[]
//  - online softmax + pool, fully unrolled (pads contribute exact zeros)
//  - T14 prefetch in 8 NAMED float4 registers (R4's array went to scratch:
//    519 MB scratch writes observed; named scalars + unconditional flow fix it)
// ---------------------------------------------------------------------------
__global__ __launch_bounds__(256, 3)
void fused_kernel(const float* __restrict__ x, const unsigned short* __restrict__ wfrag,
                  const float* __restrict__ b1, const float* __restrict__ W2,
                  const int* __restrict__ start, float* __restrict__ out, int N)
{
  __shared__ unsigned short xhi[TILE][HPAD];  // 16.9 KB
  __shared__ unsigned short xlo[TILE][HPAD];  // 16.9 KB
  __shared__ float part[4][TILE];

  const int g = blockIdx.x;
  const int tid = threadIdx.x;
  const int s = start[g], e = start[g + 1];
  if (s >= e) { out[(size_t)g * D_DIM + tid] = 0.0f; return; }
  const int len = e - s;

  const int lane = tid & 63, w = tid >> 6;
  const int q = lane >> 4, c = lane & 15;
  const int srow = tid >> 5, scol8 = (tid & 31) * 8;   // staging coords

  // W1 B-fragments: 16 x bf16x8 = 64 VGPR (coalesced, L2-resident)
  bf16x8 wf[8][2];
#pragma unroll
  for (int kt = 0; kt < 8; ++kt)
#pragma unroll
    for (int nt = 0; nt < 2; ++nt)
      wf[kt][nt] = ((const bf16x8*)wfrag)[(kt * 2 + nt) * 256 + tid];

  float b1c[2], w2c[2];
#pragma unroll
  for (int nt = 0; nt < 2; ++nt) {
    int col = w * 32 + nt * 16 + c;
    b1c[nt] = b1[col];
    w2c[nt] = W2[col];
  }

  float m_run = -INFINITY, Z = 0.0f, accd = 0.0f;
  const int nT = (len + TILE - 1) / TILE;

  // ---- prologue: stage tile 0 directly ----
  {
    const float4* g0 = reinterpret_cast<const float4*>(x + (size_t)min(s + srow,      N - 1) * D_DIM + scol8);
    const float4* g1 = reinterpret_cast<const float4*>(x + (size_t)min(s + srow +  8, N - 1) * D_DIM + scol8);
    const float4* g2 = reinterpret_cast<const float4*>(x + (size_t)min(s + srow + 16, N - 1) * D_DIM + scol8);
    const float4* g3 = reinterpret_cast<const float4*>(x + (size_t)min(s + srow + 24, N - 1) * D_DIM + scol8);
    convert_store(xhi, xlo, srow,      scol8, g0[0], g0[1]);
    convert_store(xhi, xlo, srow +  8, scol8, g1[0], g1[1]);
    convert_store(xhi, xlo, srow + 16, scol8, g2[0], g2[1]);
    convert_store(xhi, xlo, srow + 24, scol8, g3[0], g3[1]);
  }

  for (int ti = 0; ti < nT; ++ti) {
    const int t0 = ti * TILE;
    const int iend = min(TILE, len - t0);

    // ---- T14: issue next tile's loads NOW, into named registers.
    //      Unconditional (clamped addresses); last tile's data is dead.
    float4 pA0, pB0, pA1, pB1, pA2, pB2, pA3, pB3;
    {
      const int nb = s + t0 + TILE;
      const float4* g0 = reinterpret_cast<const float4*>(x + (size_t)min(nb + srow,      N - 1) * D_DIM + scol8);
      const float4* g1 = reinterpret_cast<const float4*>(x + (size_t)min(nb + srow +  8, N - 1) * D_DIM + scol8);
      const float4* g2 = reinterpret_cast<const float4*>(x + (size_t)min(nb + srow + 16, N - 1) * D_DIM + scol8);
      const float4* g3 = reinterpret_cast<const float4*>(x + (size_t)min(nb + srow + 24, N - 1) * D_DIM + scol8);
      pA0 = g0[0]; pB0 = g0[1];
      pA1 = g1[0]; pB1 = g1[1];
      pA2 = g2[0]; pB2 = g2[1];
      pA3 = g3[0]; pB3 = g3[1];
    }

    __syncthreads();   // LDS tile ti ready

    // ---- MFMA: h-tile = x_tile @ W1[:, wave's 32 cols] (hi + lo terms) ----
    f32x4 acc[2][2];
#pragma unroll
    for (int m = 0; m < 2; ++m)
#pragma unroll
      for (int nt = 0; nt < 2; ++nt) acc[m][nt] = (f32x4){0.f, 0.f, 0.f, 0.f};

#pragma unroll
    for (int kt = 0; kt < 8; ++kt) {
      const int koff = kt * 32 + q * 8;
      bf16x8 ah0 = *reinterpret_cast<const bf16x8*>(&xhi[c][koff]);
      bf16x8 al0 = *reinterpret_cast<const bf16x8*>(&xlo[c][koff]);
      bf16x8 ah1 = *reinterpret_cast<const bf16x8*>(&xhi[16 + c][koff]);
      bf16x8 al1 = *reinterpret_cast<const bf16x8*>(&xlo[16 + c][koff]);
#pragma unroll
      for (int nt = 0; nt < 2; ++nt) {
        acc[0][nt] = __builtin_amdgcn_mfma_f32_16x16x32_bf16(ah0, wf[kt][nt], acc[0][nt], 0, 0, 0);
        acc[0][nt] = __builtin_amdgcn_mfma_f32_16x16x32_bf16(al0, wf[kt][nt], acc[0][nt], 0, 0, 0);
        acc[1][nt] = __builtin_amdgcn_mfma_f32_16x16x32_bf16(ah1, wf[kt][nt], acc[1][nt], 0, 0, 0);
        acc[1][nt] = __builtin_amdgcn_mfma_f32_16x16x32_bf16(al1, wf[kt][nt], acc[1][nt], 0, 0, 0);
      }
    }

    // ---- tanh + W2 dot; reduce across the 16 col-lanes -> part[w][i] ----
#pragma unroll
    for (int m = 0; m < 2; ++m)
#pragma unroll
      for (int r = 0; r < 4; ++r) {
        float v = tanh_fast(acc[m][0][r] + b1c[0]) * w2c[0]
                + tanh_fast(acc[m][1][r] + b1c[1]) * w2c[1];
#pragma unroll
        for (int o = 1; o < 16; o <<= 1) v += __shfl_xor(v, o, 64);
        if (c == 0) part[w][m * 16 + q * 4 + r] = v;
      }
    __syncthreads();   // part ready

    // ---- online softmax + pool: fixed 32 iterations (pads are exact +0) ----
    {
      const int i = lane & 31;
      float li = (i < iend) ? (part[0][i] + part[1][i] + part[2][i] + part[3][i])
                            : -INFINITY;
      float tmax = li;
#pragma unroll
      for (int o = 1; o < 32; o <<= 1) tmax = fmaxf(tmax, __shfl_xor(tmax, o, 64));
      float m_new = fmaxf(m_run, tmax);
      float ei = __expf(li - m_new);              // 0 for pad lanes
      float esum = ei;
#pragma unroll
      for (int o = 1; o < 32; o <<= 1) esum += __shfl_xor(esum, o, 64);
      float scale = __expf(m_run - m_new);        // first tile: exp(-inf)=0
      Z = Z * scale + esum;

      float ac0 = 0.f, ac1 = 0.f, ac2 = 0.f, ac3 = 0.f;
#pragma unroll
      for (int ii = 0; ii < TILE; ii += 4) {
        float e0 = __shfl(ei, ii + 0, 64);
        float e1 = __shfl(ei, ii + 1, 64);
        float e2 = __shfl(ei, ii + 2, 64);
        float e3 = __shfl(ei, ii + 3, 64);
        float x0 = __uint_as_float((unsigned int)xhi[ii + 0][tid] << 16)
                 + __uint_as_float((unsigned int)xlo[ii + 0][tid] << 16);
        float x1 = __uint_as_float((unsigned int)xhi[ii + 1][tid] << 16)
                 + __uint_as_float((unsigned int)xlo[ii + 1][tid] << 16);
        float x2 = __uint_as_float((unsigned int)xhi[ii + 2][tid] << 16)
                 + __uint_as_float((unsigned int)xlo[ii + 2][tid] << 16);
        float x3 = __uint_as_float((unsigned int)xhi[ii + 3][tid] << 16)
                 + __uint_as_float((unsigned int)xlo[ii + 3][tid] << 16);
        ac0 = fmaf(e0, x0, ac0);
        ac1 = fmaf(e1, x1, ac1);
        ac2 = fmaf(e2, x2, ac2);
        ac3 = fmaf(e3, x3, ac3);
      }
      accd = fmaf(accd, scale, (ac0 + ac1) + (ac2 + ac3));
      m_run = m_new;
    }
    __syncthreads();   // pool done; LDS free to overwrite

    // ---- writeback prefetched tile ti+1 (unconditional; dead on last tile) ----
    convert_store(xhi, xlo, srow,      scol8, pA0, pB0);
    convert_store(xhi, xlo, srow +  8, scol8, pA1, pB1);
    convert_store(xhi, xlo, srow + 16, scol8, pA2, pB2);
    convert_store(xhi, xlo, srow + 24, scol8, pA3, pB3);
  }

  out[(size_t)g * D_DIM + tid] = accd / Z;
}

// ---------------------------------------------------------------------------
extern "C" void kernel_launch(void* const* d_in, const int* in_sizes, int n_in,
                              void* d_out, int out_size, void* d_ws, size_t ws_size,
                              hipStream_t stream)
{
  const float* x     = (const float*)d_in[0];
  const void*  batch = d_in[1];
  const float* W1    = (const float*)d_in[2];
  const float* b1    = (const float*)d_in[3];
  const float* W2    = (const float*)d_in[4];
  // d_in[5] = b2: cancels exactly in the segment softmax -> unused.

  const int N = in_sizes[0] / D_DIM;     // 500000
  const int G = out_size / D_DIM;        // 4096

  unsigned short* wfrag = (unsigned short*)d_ws;              // 64 KB
  int* startA = (int*)((char*)d_ws + 16 * 256 * 8 * sizeof(unsigned short));
  float* out = (float*)d_out;

  setup_w1_kernel<<<1, 256, 0, stream>>>(W1, wfrag);
  offsets_kernel<<<(G + 1 + 255) / 256, 256, 0, stream>>>(batch, startA, N, G);
  fused_kernel<<<G, 256, 0, stream>>>(x, wfrag, b1, W2, startA, out, N);
}